// Round 1
// baseline (62.819 us; speedup 1.0000x reference)
//
#include <hip/hip_runtime.h>

// SpikePool: [N=16,C=128,H=64,W=64,T=8] f32
//   x_out[n,c,h,w,t] = mean over {2x2 spatial} x {2 time chunks} (t in 0..3)
//   out[...,0:4]  = IF-spikes(x_out)
//   out[...,4:8]  = IF-spikes(fmod(x_out,TH) + x_out)
// One thread per output pixel (n,c,h,w): reads 2x64B rows, writes 32B.

#define TH 0.999f

__global__ __launch_bounds__(256) void spikepool_kernel(
    const float* __restrict__ x, float* __restrict__ out, int total)
{
    int idx = blockIdx.x * 256 + threadIdx.x;
    if (idx >= total) return;

    const int w  = idx & 31;         // W/2 = 32
    const int h  = (idx >> 5) & 31;  // H/2 = 32
    const int nc = idx >> 10;        // n*C + c

    // input row base (floats): nc*(64*64*8) + (2h)*(64*8) + (2w)*8
    const size_t base = (size_t)nc * 32768 + (size_t)h * 1024 + (size_t)w * 16;
    const float4* r0p = reinterpret_cast<const float4*>(x + base);        // row 2h
    const float4* r1p = r0p + 128;                                        // row 2h+1 (+512 floats)

    // r[0..7] = (w0, t0..7); r[8..15] = (w1, t0..7)
    float r0[16], r1[16];
    *reinterpret_cast<float4*>(&r0[0])  = r0p[0];
    *reinterpret_cast<float4*>(&r0[4])  = r0p[1];
    *reinterpret_cast<float4*>(&r0[8])  = r0p[2];
    *reinterpret_cast<float4*>(&r0[12]) = r0p[3];
    *reinterpret_cast<float4*>(&r1[0])  = r1p[0];
    *reinterpret_cast<float4*>(&r1[4])  = r1p[1];
    *reinterpret_cast<float4*>(&r1[8])  = r1p[2];
    *reinterpret_cast<float4*>(&r1[12]) = r1p[3];

    // x_out[t] = (S0/4 + S1/4)/2, sums left-associated in memory order
    // (x00 + x01 + x10 + x11), matching XLA's sequential reduce.
    float xo[4];
#pragma unroll
    for (int t = 0; t < 4; ++t) {
        float s0 = ((r0[t]     + r0[8 + t])  + r1[t])     + r1[8 + t];
        float s1 = ((r0[4 + t] + r0[12 + t]) + r1[4 + t]) + r1[12 + t];
        xo[t] = (s0 * 0.25f + s1 * 0.25f) * 0.5f;
    }

    float o[8];

    // train i=0: input = x_out
    {
        float v = 0.0f;
#pragma unroll
        for (int t = 0; t < 4; ++t) {
            float u = v + xo[t];
            float s = (u >= TH) ? 1.0f : 0.0f;
            o[t] = s;
            v = u - s * TH;
        }
    }
    // train i=1: input = fmod(x_out, TH) + x_out
    // x_out in [0,1) so fmod is exactly (x_out>=TH ? x_out-TH : x_out)
    {
        float v = 0.0f;
#pragma unroll
        for (int t = 0; t < 4; ++t) {
            float m  = (xo[t] >= TH) ? (xo[t] - TH) : xo[t];
            float in = m + xo[t];
            float u = v + in;
            float s = (u >= TH) ? 1.0f : 0.0f;
            o[4 + t] = s;
            v = u - s * TH;
        }
    }

    float4* op = reinterpret_cast<float4*>(out + (size_t)idx * 8);
    op[0] = make_float4(o[0], o[1], o[2], o[3]);
    op[1] = make_float4(o[4], o[5], o[6], o[7]);
}

extern "C" void kernel_launch(void* const* d_in, const int* in_sizes, int n_in,
                              void* d_out, int out_size, void* d_ws, size_t ws_size,
                              hipStream_t stream) {
    const float* x = (const float*)d_in[0];
    float* out = (float*)d_out;
    const int total = 16 * 128 * 32 * 32;  // 2,097,152 output pixels
    spikepool_kernel<<<total / 256, 256, 0, stream>>>(x, out, total);
}